// Round 1
// baseline (3039.197 us; speedup 1.0000x reference)
//
#include <hip/hip_runtime.h>
#include <hip/hip_bf16.h>
#include <math.h>

typedef unsigned short ushort_t;
typedef __attribute__((ext_vector_type(8))) short short8;
typedef __attribute__((ext_vector_type(4))) float f32x4;

#define B_ 64
#define TV_ 80
#define TD_ 19
#define H_ 512
#define VD_ 4096
#define NV_ 10000
#define G4_ 2048

__device__ __forceinline__ float bf2f(ushort_t u) {
  unsigned int x = ((unsigned int)u) << 16;
  float f;
  __builtin_memcpy(&f, &x, 4);
  return f;
}
__device__ __forceinline__ ushort_t f2bf(float f) {
  unsigned int x;
  __builtin_memcpy(&x, &f, 4);
  x = (x + 0x7FFFu + ((x >> 16) & 1u)) >> 16;
  return (ushort_t)x;
}
__device__ __forceinline__ float sigmoidf_(float x) { return 1.0f / (1.0f + expf(-x)); }

// ---------------- fp32 -> bf16 convert (n multiple of 4) ----------------
__global__ __launch_bounds__(256) void cvt_f32_bf16(const float* __restrict__ in,
                                                    ushort_t* __restrict__ outp, int n4) {
  int i = blockIdx.x * 256 + threadIdx.x;
  if (i < n4) {
    float4 v = reinterpret_cast<const float4*>(in)[i];
    ushort4 r;
    r.x = f2bf(v.x); r.y = f2bf(v.y); r.z = f2bf(v.z); r.w = f2bf(v.w);
    reinterpret_cast<ushort4*>(outp)[i] = r;
  }
}

// split convert: hi = bf16(x), lo = bf16(x - hi)
__global__ __launch_bounds__(256) void cvt_split_bf16(const float* __restrict__ in,
                                                      ushort_t* __restrict__ hi,
                                                      ushort_t* __restrict__ lo, int n4) {
  int i = blockIdx.x * 256 + threadIdx.x;
  if (i < n4) {
    float4 v = reinterpret_cast<const float4*>(in)[i];
    ushort4 rh, rl;
    rh.x = f2bf(v.x); rl.x = f2bf(v.x - bf2f(rh.x));
    rh.y = f2bf(v.y); rl.y = f2bf(v.y - bf2f(rh.y));
    rh.z = f2bf(v.z); rl.z = f2bf(v.z - bf2f(rh.z));
    rh.w = f2bf(v.w); rl.w = f2bf(v.w - bf2f(rh.w));
    reinterpret_cast<ushort4*>(hi)[i] = rh;
    reinterpret_cast<ushort4*>(lo)[i] = rl;
  }
}

// ---------------- embedding gather -> bf16 ----------------
__global__ __launch_bounds__(256) void gather_embed(const float* __restrict__ tab,
                                                    const int* __restrict__ cap,
                                                    ushort_t* __restrict__ outp) {
  int t = blockIdx.x;  // 0..18
  int b = blockIdx.y;  // 0..63
  int tok = cap[b * 20 + t];
  const float* src = tab + (size_t)tok * H_;
  ushort_t* dst = outp + ((size_t)(b * TD_ + t)) * H_;
  int i = threadIdx.x;  // 256 threads * float2 = 512
  float2 v = reinterpret_cast<const float2*>(src)[i];
  ushort2 r;
  r.x = f2bf(v.x);
  r.y = f2bf(v.y);
  reinterpret_cast<ushort2*>(dst)[i] = r;
}

// ---------------- MFMA GEMM: C(M,N) = A(M,K) * W(N,K)^T + b1 + b2 ----------------
__device__ __forceinline__ short8 zero8() {
  short8 z = {0, 0, 0, 0, 0, 0, 0, 0};
  return z;
}
__device__ __forceinline__ short8 load_afrag(const ushort_t* A, size_t off) {
  return *reinterpret_cast<const short8*>(A + off);
}
__device__ __forceinline__ short8 load_afrag(const float* A, size_t off) {
  float4 v0 = *reinterpret_cast<const float4*>(A + off);
  float4 v1 = *reinterpret_cast<const float4*>(A + off + 4);
  short8 r;
  r[0] = (short)f2bf(v0.x); r[1] = (short)f2bf(v0.y);
  r[2] = (short)f2bf(v0.z); r[3] = (short)f2bf(v0.w);
  r[4] = (short)f2bf(v1.x); r[5] = (short)f2bf(v1.y);
  r[6] = (short)f2bf(v1.z); r[7] = (short)f2bf(v1.w);
  return r;
}
__device__ __forceinline__ void store_c(float* C, size_t idx, float v) { C[idx] = v; }
__device__ __forceinline__ void store_c(ushort_t* C, size_t idx, float v) { C[idx] = f2bf(v); }

template <typename AT, typename OT>
__global__ __launch_bounds__(256) void gemm_nt_mfma(const AT* __restrict__ A,
                                                    const ushort_t* __restrict__ W,
                                                    const float* __restrict__ bias1,
                                                    const float* __restrict__ bias2,
                                                    OT* __restrict__ C, int M, int N, int K) {
  int tid = threadIdx.x;
  int l = tid & 63, w = tid >> 6;
  int wm = w >> 1, wn = w & 1;
  int row0 = blockIdx.y * 64 + wm * 32;
  int col0 = blockIdx.x * 64 + wn * 32;
  int lr = l & 15;
  int kb = (l >> 4) << 3;
  int ar0 = row0 + lr, ar1 = row0 + 16 + lr;
  int wr0 = col0 + lr, wr1 = col0 + 16 + lr;
  bool aok0 = ar0 < M, aok1 = ar1 < M;
  bool wok0 = wr0 < N, wok1 = wr1 < N;
  f32x4 acc00 = {0.f, 0.f, 0.f, 0.f}, acc01 = acc00, acc10 = acc00, acc11 = acc00;
#pragma unroll 2
  for (int k0 = 0; k0 < K; k0 += 32) {
    int k = k0 + kb;
    short8 a0 = aok0 ? load_afrag(A, (size_t)ar0 * K + k) : zero8();
    short8 a1 = aok1 ? load_afrag(A, (size_t)ar1 * K + k) : zero8();
    short8 b0 = wok0 ? load_afrag(W, (size_t)wr0 * K + k) : zero8();
    short8 b1 = wok1 ? load_afrag(W, (size_t)wr1 * K + k) : zero8();
    acc00 = __builtin_amdgcn_mfma_f32_16x16x32_bf16(a0, b0, acc00, 0, 0, 0);
    acc01 = __builtin_amdgcn_mfma_f32_16x16x32_bf16(a0, b1, acc01, 0, 0, 0);
    acc10 = __builtin_amdgcn_mfma_f32_16x16x32_bf16(a1, b0, acc10, 0, 0, 0);
    acc11 = __builtin_amdgcn_mfma_f32_16x16x32_bf16(a1, b1, acc11, 0, 0, 0);
  }
  int rb = (l >> 4) << 2;
#pragma unroll
  for (int i = 0; i < 2; ++i) {
#pragma unroll
    for (int v = 0; v < 4; ++v) {
      int r = row0 + i * 16 + rb + v;
      if (r < M) {
#pragma unroll
        for (int j = 0; j < 2; ++j) {
          int cc = col0 + j * 16 + lr;
          if (cc < N) {
            float av;
            if (i == 0) av = (j == 0) ? acc00[v] : acc01[v];
            else        av = (j == 0) ? acc10[v] : acc11[v];
            if (bias1) av += bias1[cc];
            if (bias2) av += bias2[cc];
            store_c(C, (size_t)r * N + cc, av);
          }
        }
      }
    }
  }
}

// ---------------- fused LSTM step ----------------
// grid 128 blocks (4 h-cols each), 256 threads (4 waves; wave w = batch rows w*16..w*16+15)
// block computes the 16 gate columns {g*512 + s0 + sc : g in 0..3, sc in 0..3},
// g = h_prev @ whh^T (split-bf16, 3 MFMA terms) + xg[:,t,:], then gate math.
__global__ __launch_bounds__(256) void lstm_step_mfma(
    const float* __restrict__ xg, const ushort_t* __restrict__ whh_hi,
    const ushort_t* __restrict__ whh_lo, const ushort_t* __restrict__ hprev, int hstride,
    const ushort_t* __restrict__ hlo_prev, float* __restrict__ c, ushort_t* __restrict__ hs,
    ushort_t* __restrict__ hlo_out, int t, int T) {
  __shared__ float gbuf[64][17];
  int tid = threadIdx.x;
  int l = tid & 63, w = tid >> 6;
  int s0 = blockIdx.x << 2;
  int lr = l & 15, kb = (l >> 4) << 3;
  int arow = (w << 4) + lr;
  int gate = lr >> 2, sc = lr & 3;
  int wrow = gate * H_ + s0 + sc;
  const ushort_t* ap = hprev + (size_t)arow * hstride + kb;
  const ushort_t* alp = hlo_prev + (size_t)arow * H_ + kb;
  const ushort_t* bp = whh_hi + (size_t)wrow * H_ + kb;
  const ushort_t* blp = whh_lo + (size_t)wrow * H_ + kb;
  f32x4 acc = {0.f, 0.f, 0.f, 0.f};
#pragma unroll 4
  for (int k0 = 0; k0 < H_; k0 += 32) {
    short8 a = *reinterpret_cast<const short8*>(ap + k0);
    short8 al = *reinterpret_cast<const short8*>(alp + k0);
    short8 b = *reinterpret_cast<const short8*>(bp + k0);
    short8 bl = *reinterpret_cast<const short8*>(blp + k0);
    acc = __builtin_amdgcn_mfma_f32_16x16x32_bf16(a, b, acc, 0, 0, 0);
    acc = __builtin_amdgcn_mfma_f32_16x16x32_bf16(al, b, acc, 0, 0, 0);
    acc = __builtin_amdgcn_mfma_f32_16x16x32_bf16(a, bl, acc, 0, 0, 0);
  }
  int rb = (w << 4) + ((l >> 4) << 2);
#pragma unroll
  for (int v = 0; v < 4; ++v) gbuf[rb + v][lr] = acc[v];
  __syncthreads();
  int row = tid >> 2, s = tid & 3;
  size_t xb = ((size_t)row * T + t) * G4_ + s0 + s;
  float gi = gbuf[row][0 + s] + xg[xb];
  float gf = gbuf[row][4 + s] + xg[xb + 512];
  float gg = gbuf[row][8 + s] + xg[xb + 1024];
  float go = gbuf[row][12 + s] + xg[xb + 1536];
  size_t ci = (size_t)row * H_ + s0 + s;
  float cv = sigmoidf_(gf) * c[ci] + sigmoidf_(gi) * tanhf(gg);
  float hv = sigmoidf_(go) * tanhf(cv);
  c[ci] = cv;
  ushort_t hhi = f2bf(hv);
  hs[((size_t)row * T + t) * H_ + s0 + s] = hhi;
  hlo_out[ci] = f2bf(hv - bf2f(hhi));
}

// ---------------- MHA (fp32) ----------------
// grid (NH, B); per block: one (b, head). Q 19x128, K/V 80x128.
__global__ __launch_bounds__(256) void mha_kernel(const float* __restrict__ Qf,
                                                  const float* __restrict__ Kf,
                                                  const float* __restrict__ Vf,
                                                  ushort_t* __restrict__ attnout) {
  __shared__ float Qs[19][132];
  __shared__ float Ks[80][132];
  __shared__ float Ss[19][80];
  int h = blockIdx.x, b = blockIdx.y;
  int tid = threadIdx.x;
  for (int idx = tid; idx < 19 * 128; idx += 256) {
    int q = idx >> 7, d = idx & 127;
    Qs[q][d] = Qf[((size_t)(b * TD_ + q)) * H_ + h * 128 + d];
  }
  for (int idx = tid; idx < 80 * 128; idx += 256) {
    int k = idx >> 7, d = idx & 127;
    Ks[k][d] = Kf[((size_t)(b * TV_ + k)) * H_ + h * 128 + d];
  }
  __syncthreads();
  // scores
  for (int u = tid; u < 240; u += 256) {
    int k = u / 3, qo = u % 3;
    int q0 = qo * 8;
    int nq = (qo == 2) ? 3 : 8;
    float s[8] = {0.f, 0.f, 0.f, 0.f, 0.f, 0.f, 0.f, 0.f};
    for (int d = 0; d < 128; d += 4) {
      float4 kv = *reinterpret_cast<const float4*>(&Ks[k][d]);
#pragma unroll
      for (int qi = 0; qi < 8; ++qi) {
        if (qi < nq) {
          float4 qv = *reinterpret_cast<const float4*>(&Qs[q0 + qi][d]);
          s[qi] += qv.x * kv.x + qv.y * kv.y + qv.z * kv.z + qv.w * kv.w;
        }
      }
    }
    for (int qi = 0; qi < nq; ++qi) Ss[q0 + qi][k] = s[qi] * 0.08838834764831845f;
  }
  __syncthreads();
  if (tid < 19) {
    float m = -1e30f;
    for (int k = 0; k < 80; ++k) m = fmaxf(m, Ss[tid][k]);
    float sum = 0.f;
    for (int k = 0; k < 80; ++k) {
      float e = expf(Ss[tid][k] - m);
      Ss[tid][k] = e;
      sum += e;
    }
    float inv = 1.0f / sum;
    for (int k = 0; k < 80; ++k) Ss[tid][k] *= inv;
  }
  __syncthreads();
  // out = P @ V : units (q-pair, d-octet)
  for (int u = tid; u < 160; u += 256) {
    int qp = u / 16, d0 = (u % 16) * 8;
    int q0 = qp * 2;
    int nq = (q0 + 1 < 19) ? 2 : 1;
    float o0[8] = {0.f, 0.f, 0.f, 0.f, 0.f, 0.f, 0.f, 0.f};
    float o1[8] = {0.f, 0.f, 0.f, 0.f, 0.f, 0.f, 0.f, 0.f};
#pragma unroll 4
    for (int k = 0; k < 80; ++k) {
      const float* vp = Vf + ((size_t)(b * TV_ + k)) * H_ + h * 128 + d0;
      float4 v0 = *reinterpret_cast<const float4*>(vp);
      float4 v1 = *reinterpret_cast<const float4*>(vp + 4);
      float p0 = Ss[q0][k];
      o0[0] += p0 * v0.x; o0[1] += p0 * v0.y; o0[2] += p0 * v0.z; o0[3] += p0 * v0.w;
      o0[4] += p0 * v1.x; o0[5] += p0 * v1.y; o0[6] += p0 * v1.z; o0[7] += p0 * v1.w;
      if (nq == 2) {
        float p1 = Ss[q0 + 1][k];
        o1[0] += p1 * v0.x; o1[1] += p1 * v0.y; o1[2] += p1 * v0.z; o1[3] += p1 * v0.w;
        o1[4] += p1 * v1.x; o1[5] += p1 * v1.y; o1[6] += p1 * v1.z; o1[7] += p1 * v1.w;
      }
    }
    for (int j = 0; j < 8; ++j)
      attnout[((size_t)(b * TD_ + q0)) * H_ + h * 128 + d0 + j] = f2bf(o0[j]);
    if (nq == 2)
      for (int j = 0; j < 8; ++j)
        attnout[((size_t)(b * TD_ + q0 + 1)) * H_ + h * 128 + d0 + j] = f2bf(o1[j]);
  }
}

// ---------------- host ----------------
template <typename AT, typename OT>
static void launch_gemm(const AT* A, const ushort_t* W, const float* b1, const float* b2,
                        OT* C, int M, int N, int K, hipStream_t s) {
  dim3 g((N + 63) / 64, (M + 63) / 64);
  gemm_nt_mfma<AT, OT><<<g, dim3(256), 0, s>>>(A, W, b1, b2, C, M, N, K);
}

extern "C" void kernel_launch(void* const* d_in, const int* in_sizes, int n_in, void* d_out,
                              int out_size, void* d_ws, size_t ws_size, hipStream_t stream) {
  const float* video = (const float*)d_in[0];
  const int* captions = (const int*)d_in[1];
  const float* vpw = (const float*)d_in[2];
  const float* vpb = (const float*)d_in[3];
  const float* emb_table = (const float*)d_in[4];
  const float* wih[4] = {(const float*)d_in[5], (const float*)d_in[9], (const float*)d_in[13],
                         (const float*)d_in[17]};
  const float* whh[4] = {(const float*)d_in[6], (const float*)d_in[10], (const float*)d_in[14],
                         (const float*)d_in[18]};
  const float* bih[4] = {(const float*)d_in[7], (const float*)d_in[11], (const float*)d_in[15],
                         (const float*)d_in[19]};
  const float* bhh[4] = {(const float*)d_in[8], (const float*)d_in[12], (const float*)d_in[16],
                         (const float*)d_in[20]};
  const float* a_inw = (const float*)d_in[21];
  const float* a_inb = (const float*)d_in[22];
  const float* a_outw = (const float*)d_in[23];
  const float* a_outb = (const float*)d_in[24];
  const float* ow = (const float*)d_in[25];
  const float* ob = (const float*)d_in[26];
  float* out = (float*)d_out;

  char* ws = (char*)d_ws;
  size_t o = 0;
  auto take = [&](size_t bytes) {
    size_t cur = o;
    o += (bytes + 255) & ~(size_t)255;
    return cur;
  };
  const size_t o_vpw = take((size_t)H_ * VD_ * 2);
  size_t o_wih[4], o_whh[4], o_whl[4];
  for (int i = 0; i < 4; ++i) {
    o_wih[i] = take((size_t)G4_ * H_ * 2);
    o_whh[i] = take((size_t)G4_ * H_ * 2);
    o_whl[i] = take((size_t)G4_ * H_ * 2);
  }
  const size_t o_ainw = take((size_t)3 * H_ * H_ * 2);
  const size_t o_aoutw = take((size_t)H_ * H_ * 2);
  const size_t o_ow = take((size_t)NV_ * H_ * 2);
  const size_t o_vproj = take((size_t)B_ * TV_ * H_ * 2);
  const size_t o_xg = take((size_t)B_ * TV_ * G4_ * 4);  // 41,943,040 B, reused
  const size_t o_hse0 = take((size_t)B_ * TV_ * H_ * 2);
  const size_t o_hse1 = take((size_t)B_ * TV_ * H_ * 2);
  const size_t o_emb = take((size_t)B_ * TD_ * H_ * 2);
  const size_t o_attn = take((size_t)B_ * TD_ * H_ * 2);
  const size_t o_attd = take((size_t)B_ * TD_ * H_ * 2);
  const size_t o_hsd0 = take((size_t)B_ * TD_ * H_ * 2);
  const size_t o_hsd1 = take((size_t)B_ * TD_ * H_ * 2);
  const size_t o_h0 = take((size_t)B_ * H_ * 2);
  const size_t o_hloA = take((size_t)B_ * H_ * 2);
  const size_t o_hloB = take((size_t)B_ * H_ * 2);
  const size_t o_c = take((size_t)B_ * H_ * 4);
  // Q/K/V fp32 overlaid on tail of xg region (dead there during attention)
  const size_t o_Q = o_xg + 18481152;           // 1216*512*4 = 2,490,368
  const size_t o_K = o_Q + 2490368;             // 5120*512*4 = 10,485,760
  const size_t o_V = o_K + 10485760;            // ends exactly at o_xg + 41,943,040

  ushort_t* vpw_bf = (ushort_t*)(ws + o_vpw);
  ushort_t* ainw_bf = (ushort_t*)(ws + o_ainw);
  ushort_t* aoutw_bf = (ushort_t*)(ws + o_aoutw);
  ushort_t* ow_bf = (ushort_t*)(ws + o_ow);
  ushort_t* vproj_bf = (ushort_t*)(ws + o_vproj);
  float* xg = (float*)(ws + o_xg);
  ushort_t* hse0 = (ushort_t*)(ws + o_hse0);
  ushort_t* hse1 = (ushort_t*)(ws + o_hse1);
  ushort_t* emb_bf = (ushort_t*)(ws + o_emb);
  ushort_t* attn_bf = (ushort_t*)(ws + o_attn);
  ushort_t* attd_bf = (ushort_t*)(ws + o_attd);
  ushort_t* hsd0 = (ushort_t*)(ws + o_hsd0);
  ushort_t* hsd1 = (ushort_t*)(ws + o_hsd1);
  ushort_t* h0 = (ushort_t*)(ws + o_h0);
  ushort_t* hloA = (ushort_t*)(ws + o_hloA);
  ushort_t* hloB = (ushort_t*)(ws + o_hloB);
  float* cbuf = (float*)(ws + o_c);
  float* Qf = (float*)(ws + o_Q);
  float* Kf = (float*)(ws + o_K);
  float* Vf = (float*)(ws + o_V);

  auto cvt = [&](const float* in, ushort_t* outp, size_t n) {
    int n4 = (int)(n / 4);
    cvt_f32_bf16<<<dim3((n4 + 255) / 256), dim3(256), 0, stream>>>(in, outp, n4);
  };
  // weight conversions
  cvt(vpw, vpw_bf, (size_t)H_ * VD_);
  for (int i = 0; i < 4; ++i) {
    cvt(wih[i], (ushort_t*)(ws + o_wih[i]), (size_t)G4_ * H_);
    int n4 = (int)((size_t)G4_ * H_ / 4);
    cvt_split_bf16<<<dim3((n4 + 255) / 256), dim3(256), 0, stream>>>(
        whh[i], (ushort_t*)(ws + o_whh[i]), (ushort_t*)(ws + o_whl[i]), n4);
  }
  cvt(a_inw, ainw_bf, (size_t)3 * H_ * H_);
  cvt(a_outw, aoutw_bf, (size_t)H_ * H_);
  cvt(ow, ow_bf, (size_t)NV_ * H_);
  hipMemsetAsync(h0, 0, (size_t)B_ * H_ * 2, stream);

  // vproj: (5120,4096) x (512,4096)^T -> bf16
  launch_gemm<float, ushort_t>(video, vpw_bf, vpb, nullptr, vproj_bf, B_ * TV_, H_, VD_, stream);

  auto run_lstm = [&](const ushort_t* x_bf, int T, int layer, ushort_t* hs_out) {
    int M = B_ * T;
    launch_gemm<ushort_t, float>(x_bf, (const ushort_t*)(ws + o_wih[layer]), bih[layer],
                                 bhh[layer], xg, M, G4_, H_, stream);
    hipMemsetAsync(cbuf, 0, (size_t)B_ * H_ * 4, stream);
    for (int t = 0; t < T; ++t) {
      const ushort_t* hp = (t == 0) ? h0 : (hs_out + (size_t)(t - 1) * H_);
      int hstride = (t == 0) ? H_ : (T * H_);
      const ushort_t* hlp = (t == 0) ? h0 : ((t & 1) ? hloA : hloB);
      ushort_t* hlo = (t & 1) ? hloB : hloA;
      lstm_step_mfma<<<dim3(128), dim3(256), 0, stream>>>(
          xg, (const ushort_t*)(ws + o_whh[layer]), (const ushort_t*)(ws + o_whl[layer]), hp,
          hstride, hlp, cbuf, hs_out, hlo, t, T);
    }
  };

  run_lstm(vproj_bf, TV_, 0, hse0);
  run_lstm(hse0, TV_, 1, hse1);

  gather_embed<<<dim3(TD_, B_), dim3(256), 0, stream>>>(emb_table, captions, emb_bf);

  launch_gemm<ushort_t, float>(emb_bf, ainw_bf, a_inb, nullptr, Qf, B_ * TD_, H_, H_, stream);
  launch_gemm<ushort_t, float>(hse1, ainw_bf + (size_t)H_ * H_, a_inb + H_, nullptr, Kf,
                               B_ * TV_, H_, H_, stream);
  launch_gemm<ushort_t, float>(hse1, ainw_bf + (size_t)2 * H_ * H_, a_inb + 2 * H_, nullptr, Vf,
                               B_ * TV_, H_, H_, stream);

  mha_kernel<<<dim3(4, B_), dim3(256), 0, stream>>>(Qf, Kf, Vf, attn_bf);

  launch_gemm<ushort_t, ushort_t>(attn_bf, aoutw_bf, a_outb, nullptr, attd_bf, B_ * TD_, H_, H_,
                                  stream);

  run_lstm(attd_bf, TD_, 2, hsd0);
  run_lstm(hsd0, TD_, 3, hsd1);

  launch_gemm<ushort_t, float>(hsd1, ow_bf, ob, nullptr, out, B_ * TD_, NV_, H_, stream);
}

// Round 2
// 1890.865 us; speedup vs baseline: 1.6073x; 1.6073x over previous
//
#include <hip/hip_runtime.h>
#include <hip/hip_bf16.h>
#include <math.h>

typedef unsigned short ushort_t;
typedef __attribute__((ext_vector_type(8))) short short8;
typedef __attribute__((ext_vector_type(4))) float f32x4;

#define B_ 64
#define TV_ 80
#define TD_ 19
#define H_ 512
#define VD_ 4096
#define NV_ 10000
#define G4_ 2048

__device__ __forceinline__ float bf2f(ushort_t u) {
  unsigned int x = ((unsigned int)u) << 16;
  float f;
  __builtin_memcpy(&f, &x, 4);
  return f;
}
__device__ __forceinline__ ushort_t f2bf(float f) {
  unsigned int x;
  __builtin_memcpy(&x, &f, 4);
  x = (x + 0x7FFFu + ((x >> 16) & 1u)) >> 16;
  return (ushort_t)x;
}
__device__ __forceinline__ float sigmoidf_(float x) { return 1.0f / (1.0f + expf(-x)); }
__device__ __forceinline__ short8 zero8() {
  short8 z = {0, 0, 0, 0, 0, 0, 0, 0};
  return z;
}

// ---------------- fp32 -> bf16 convert (n multiple of 4) ----------------
__global__ __launch_bounds__(256) void cvt_f32_bf16(const float* __restrict__ in,
                                                    ushort_t* __restrict__ outp, int n4) {
  int i = blockIdx.x * 256 + threadIdx.x;
  if (i < n4) {
    float4 v = reinterpret_cast<const float4*>(in)[i];
    ushort4 r;
    r.x = f2bf(v.x); r.y = f2bf(v.y); r.z = f2bf(v.z); r.w = f2bf(v.w);
    reinterpret_cast<ushort4*>(outp)[i] = r;
  }
}

// ---------------- whh: split (hi+lo) + gate-tile permute ----------------
// out row p = tile*16 + gate*4 + sc  <=  src row gate*512 + tile*4 + sc
__global__ __launch_bounds__(64) void permute_split_whh(const float* __restrict__ src,
                                                        ushort_t* __restrict__ hi,
                                                        ushort_t* __restrict__ lo) {
  int p = blockIdx.x;  // 0..2047
  int tile = p >> 4, r = p & 15, gate = r >> 2, sc = r & 3;
  const float* s = src + ((size_t)(gate * H_ + tile * 4 + sc)) * H_;
  int i = threadIdx.x * 8;
  float4 v0 = *reinterpret_cast<const float4*>(s + i);
  float4 v1 = *reinterpret_cast<const float4*>(s + i + 4);
  ushort_t* hp = hi + (size_t)p * H_ + i;
  ushort_t* lp = lo + (size_t)p * H_ + i;
  ushort4 rh0, rl0, rh1, rl1;
  rh0.x = f2bf(v0.x); rl0.x = f2bf(v0.x - bf2f(rh0.x));
  rh0.y = f2bf(v0.y); rl0.y = f2bf(v0.y - bf2f(rh0.y));
  rh0.z = f2bf(v0.z); rl0.z = f2bf(v0.z - bf2f(rh0.z));
  rh0.w = f2bf(v0.w); rl0.w = f2bf(v0.w - bf2f(rh0.w));
  rh1.x = f2bf(v1.x); rl1.x = f2bf(v1.x - bf2f(rh1.x));
  rh1.y = f2bf(v1.y); rl1.y = f2bf(v1.y - bf2f(rh1.y));
  rh1.z = f2bf(v1.z); rl1.z = f2bf(v1.z - bf2f(rh1.z));
  rh1.w = f2bf(v1.w); rl1.w = f2bf(v1.w - bf2f(rh1.w));
  reinterpret_cast<ushort4*>(hp)[0] = rh0;
  reinterpret_cast<ushort4*>(hp)[1] = rh1;
  reinterpret_cast<ushort4*>(lp)[0] = rl0;
  reinterpret_cast<ushort4*>(lp)[1] = rl1;
}

// wih: cvt + gate-tile permute (hi only)
__global__ __launch_bounds__(64) void permute_cvt_wih(const float* __restrict__ src,
                                                      ushort_t* __restrict__ hi) {
  int p = blockIdx.x;
  int tile = p >> 4, r = p & 15, gate = r >> 2, sc = r & 3;
  const float* s = src + ((size_t)(gate * H_ + tile * 4 + sc)) * H_;
  int i = threadIdx.x * 8;
  float4 v0 = *reinterpret_cast<const float4*>(s + i);
  float4 v1 = *reinterpret_cast<const float4*>(s + i + 4);
  ushort_t* hp = hi + (size_t)p * H_ + i;
  ushort4 rh0, rh1;
  rh0.x = f2bf(v0.x); rh0.y = f2bf(v0.y); rh0.z = f2bf(v0.z); rh0.w = f2bf(v0.w);
  rh1.x = f2bf(v1.x); rh1.y = f2bf(v1.y); rh1.z = f2bf(v1.z); rh1.w = f2bf(v1.w);
  reinterpret_cast<ushort4*>(hp)[0] = rh0;
  reinterpret_cast<ushort4*>(hp)[1] = rh1;
}

// bc[q] = bih[src] + bhh[src], q in permuted order
__global__ __launch_bounds__(256) void combine_bias_perm(const float* __restrict__ bih,
                                                         const float* __restrict__ bhh,
                                                         float* __restrict__ bc) {
  int q = blockIdx.x * 256 + threadIdx.x;  // 0..2047
  int tile = q >> 4, r = q & 15, gate = r >> 2, sc = r & 3;
  int src = gate * H_ + tile * 4 + sc;
  bc[q] = bih[src] + bhh[src];
}

// ---------------- embedding gather -> bf16 ----------------
__global__ __launch_bounds__(256) void gather_embed(const float* __restrict__ tab,
                                                    const int* __restrict__ cap,
                                                    ushort_t* __restrict__ outp) {
  int t = blockIdx.x;  // 0..18
  int b = blockIdx.y;  // 0..63
  int tok = cap[b * 20 + t];
  const float* src = tab + (size_t)tok * H_;
  ushort_t* dst = outp + ((size_t)(b * TD_ + t)) * H_;
  int i = threadIdx.x;
  float2 v = reinterpret_cast<const float2*>(src)[i];
  ushort2 r;
  r.x = f2bf(v.x);
  r.y = f2bf(v.y);
  reinterpret_cast<ushort2*>(dst)[i] = r;
}

// ---------------- small-tile GEMM (64x64/block): C = A(M,K)*W(N,K)^T + b ----------------
__device__ __forceinline__ void store_c(float* C, size_t idx, float v) { C[idx] = v; }
__device__ __forceinline__ void store_c(ushort_t* C, size_t idx, float v) { C[idx] = f2bf(v); }

template <typename OT>
__global__ __launch_bounds__(256) void gemm_nt_mfma(const ushort_t* __restrict__ A,
                                                    const ushort_t* __restrict__ W,
                                                    const float* __restrict__ bias1,
                                                    const float* __restrict__ bias2,
                                                    OT* __restrict__ C, int M, int N, int K) {
  int tid = threadIdx.x;
  int l = tid & 63, w = tid >> 6;
  int wm = w >> 1, wn = w & 1;
  int row0 = blockIdx.y * 64 + wm * 32;
  int col0 = blockIdx.x * 64 + wn * 32;
  int lr = l & 15;
  int kb = (l >> 4) << 3;
  int ar0 = row0 + lr, ar1 = row0 + 16 + lr;
  int wr0 = col0 + lr, wr1 = col0 + 16 + lr;
  bool aok0 = ar0 < M, aok1 = ar1 < M;
  bool wok0 = wr0 < N, wok1 = wr1 < N;
  f32x4 acc00 = {0.f, 0.f, 0.f, 0.f}, acc01 = acc00, acc10 = acc00, acc11 = acc00;
#pragma unroll 2
  for (int k0 = 0; k0 < K; k0 += 32) {
    int k = k0 + kb;
    short8 a0 = aok0 ? *reinterpret_cast<const short8*>(A + (size_t)ar0 * K + k) : zero8();
    short8 a1 = aok1 ? *reinterpret_cast<const short8*>(A + (size_t)ar1 * K + k) : zero8();
    short8 b0 = wok0 ? *reinterpret_cast<const short8*>(W + (size_t)wr0 * K + k) : zero8();
    short8 b1 = wok1 ? *reinterpret_cast<const short8*>(W + (size_t)wr1 * K + k) : zero8();
    acc00 = __builtin_amdgcn_mfma_f32_16x16x32_bf16(a0, b0, acc00, 0, 0, 0);
    acc01 = __builtin_amdgcn_mfma_f32_16x16x32_bf16(a0, b1, acc01, 0, 0, 0);
    acc10 = __builtin_amdgcn_mfma_f32_16x16x32_bf16(a1, b0, acc10, 0, 0, 0);
    acc11 = __builtin_amdgcn_mfma_f32_16x16x32_bf16(a1, b1, acc11, 0, 0, 0);
  }
  int rb = (l >> 4) << 2;
#pragma unroll
  for (int i = 0; i < 2; ++i) {
#pragma unroll
    for (int v = 0; v < 4; ++v) {
      int r = row0 + i * 16 + rb + v;
      if (r < M) {
#pragma unroll
        for (int j = 0; j < 2; ++j) {
          int cc = col0 + j * 16 + lr;
          if (cc < N) {
            float av;
            if (i == 0) av = (j == 0) ? acc00[v] : acc01[v];
            else        av = (j == 0) ? acc10[v] : acc11[v];
            if (bias1) av += bias1[cc];
            if (bias2) av += bias2[cc];
            store_c(C, (size_t)r * N + cc, av);
          }
        }
      }
    }
  }
}

// ---------------- big-tile GEMM (64 rows x 256 cols / block; wave = 64x64) ----------------
// requires M % 64 == 0; N guarded.
template <typename OT>
__global__ __launch_bounds__(256) void gemm_nt_big(const ushort_t* __restrict__ A,
                                                   const ushort_t* __restrict__ W,
                                                   const float* __restrict__ bias1,
                                                   const float* __restrict__ bias2,
                                                   OT* __restrict__ C, int M, int N, int K) {
  int tid = threadIdx.x;
  int l = tid & 63, w = tid >> 6;
  int row0 = blockIdx.y * 64;
  int col0 = blockIdx.x * 256 + w * 64;
  int lr = l & 15, kb = (l >> 4) << 3;
  f32x4 acc[4][4];
#pragma unroll
  for (int i = 0; i < 4; ++i)
#pragma unroll
    for (int j = 0; j < 4; ++j) acc[i][j] = (f32x4){0.f, 0.f, 0.f, 0.f};
  const ushort_t* aps[4];
  const ushort_t* wps[4];
  bool wok[4];
#pragma unroll
  for (int fi = 0; fi < 4; ++fi) aps[fi] = A + (size_t)(row0 + fi * 16 + lr) * K + kb;
#pragma unroll
  for (int fj = 0; fj < 4; ++fj) {
    int wr = col0 + fj * 16 + lr;
    wok[fj] = wr < N;
    wps[fj] = W + (size_t)(wok[fj] ? wr : 0) * K + kb;
  }
#pragma unroll 2
  for (int k0 = 0; k0 < K; k0 += 32) {
    short8 af[4], bf[4];
#pragma unroll
    for (int fi = 0; fi < 4; ++fi) af[fi] = *reinterpret_cast<const short8*>(aps[fi] + k0);
#pragma unroll
    for (int fj = 0; fj < 4; ++fj)
      bf[fj] = wok[fj] ? *reinterpret_cast<const short8*>(wps[fj] + k0) : zero8();
#pragma unroll
    for (int fi = 0; fi < 4; ++fi)
#pragma unroll
      for (int fj = 0; fj < 4; ++fj)
        acc[fi][fj] = __builtin_amdgcn_mfma_f32_16x16x32_bf16(af[fi], bf[fj], acc[fi][fj], 0, 0, 0);
  }
  int rb = (l >> 4) << 2;
#pragma unroll
  for (int fi = 0; fi < 4; ++fi) {
#pragma unroll
    for (int v = 0; v < 4; ++v) {
      int r = row0 + fi * 16 + rb + v;
#pragma unroll
      for (int fj = 0; fj < 4; ++fj) {
        int cc = col0 + fj * 16 + lr;
        if (cc < N) {
          float av = acc[fi][fj][v];
          if (bias1) av += bias1[cc];
          if (bias2) av += bias2[cc];
          store_c(C, (size_t)r * N + cc, av);
        }
      }
    }
  }
}

// ---------------- fused LSTM pair step (diagonal pipelining) ----------------
// Per tile (128 per layer): 16 gate cols {gate*512 + tile*4 + sc}. Permuted weights:
// row p = tile*16 + gate*4 + sc. h/hlo compact [2][64][512] ping-pong.
template <bool HASX>
__device__ __forceinline__ void lstm_tile_core(
    int tile, const float* __restrict__ xg, const float* __restrict__ bc,
    const ushort_t* __restrict__ whh_hi, const ushort_t* __restrict__ whh_lo,
    const ushort_t* __restrict__ wih_p, const ushort_t* __restrict__ xh,
    const ushort_t* __restrict__ hprev, const ushort_t* __restrict__ hloprev,
    float* __restrict__ c, ushort_t* __restrict__ hout, ushort_t* __restrict__ hloout,
    ushort_t* __restrict__ hs, int t, int T) {
  __shared__ float gbuf[64][17];
  int tid = threadIdx.x;
  int l = tid & 63, w = tid >> 6;
  int s0 = tile << 2;
  int lr = l & 15, kb = (l >> 4) << 3;
  int arow = (w << 4) + lr;
  int prow = tile * 16 + lr;
  const ushort_t* ap = hprev + arow * H_ + kb;
  const ushort_t* alp = hloprev + arow * H_ + kb;
  const ushort_t* bp = whh_hi + prow * H_ + kb;
  const ushort_t* blp = whh_lo + prow * H_ + kb;
  const ushort_t* xp = HASX ? xh + arow * H_ + kb : nullptr;
  const ushort_t* wp = HASX ? wih_p + prow * H_ + kb : nullptr;
  f32x4 acc = {0.f, 0.f, 0.f, 0.f};
#pragma unroll 4
  for (int k0 = 0; k0 < H_; k0 += 32) {
    short8 a = *reinterpret_cast<const short8*>(ap + k0);
    short8 al = *reinterpret_cast<const short8*>(alp + k0);
    short8 b = *reinterpret_cast<const short8*>(bp + k0);
    short8 bl = *reinterpret_cast<const short8*>(blp + k0);
    acc = __builtin_amdgcn_mfma_f32_16x16x32_bf16(a, b, acc, 0, 0, 0);
    acc = __builtin_amdgcn_mfma_f32_16x16x32_bf16(al, b, acc, 0, 0, 0);
    acc = __builtin_amdgcn_mfma_f32_16x16x32_bf16(a, bl, acc, 0, 0, 0);
    if (HASX) {
      short8 x = *reinterpret_cast<const short8*>(xp + k0);
      short8 wf = *reinterpret_cast<const short8*>(wp + k0);
      acc = __builtin_amdgcn_mfma_f32_16x16x32_bf16(x, wf, acc, 0, 0, 0);
    }
  }
  int rb = (w << 4) + ((l >> 4) << 2);
#pragma unroll
  for (int v = 0; v < 4; ++v) gbuf[rb + v][lr] = acc[v];
  __syncthreads();
  int row = tid >> 2, s = tid & 3;
  float gi, gf, gg, go;
  if (HASX) {
    gi = gbuf[row][0 + s] + bc[tile * 16 + 0 + s];
    gf = gbuf[row][4 + s] + bc[tile * 16 + 4 + s];
    gg = gbuf[row][8 + s] + bc[tile * 16 + 8 + s];
    go = gbuf[row][12 + s] + bc[tile * 16 + 12 + s];
  } else {
    size_t xb = ((size_t)row * T + t) * G4_ + s0 + s;
    gi = gbuf[row][0 + s] + xg[xb];
    gf = gbuf[row][4 + s] + xg[xb + 512];
    gg = gbuf[row][8 + s] + xg[xb + 1024];
    go = gbuf[row][12 + s] + xg[xb + 1536];
  }
  int ci = row * H_ + s0 + s;
  float cv = sigmoidf_(gf) * c[ci] + sigmoidf_(gi) * tanhf(gg);
  float hv = sigmoidf_(go) * tanhf(cv);
  c[ci] = cv;
  ushort_t hh = f2bf(hv);
  hout[ci] = hh;
  hloout[ci] = f2bf(hv - bf2f(hh));
  if (hs) hs[((size_t)row * T + t) * H_ + s0 + s] = hh;
}

__global__ __launch_bounds__(256) void lstm_pair_step(
    const float* __restrict__ xgA, const ushort_t* __restrict__ whhA_hi,
    const ushort_t* __restrict__ whhA_lo, ushort_t* __restrict__ hA,
    ushort_t* __restrict__ hAlo, float* __restrict__ cA,
    const ushort_t* __restrict__ whhB_hi, const ushort_t* __restrict__ whhB_lo,
    const ushort_t* __restrict__ wihB, const float* __restrict__ bcB,
    ushort_t* __restrict__ hB, ushort_t* __restrict__ hBlo, float* __restrict__ cB,
    ushort_t* __restrict__ hsB, int wv, int T) {
  int half = blockIdx.x >> 7;
  int tile = blockIdx.x & 127;
  const int HN = B_ * H_;  // elements per h buffer
  if (half == 0) {
    int t = wv;
    if (t >= T) return;
    lstm_tile_core<false>(tile, xgA, nullptr, whhA_hi, whhA_lo, nullptr, nullptr,
                          hA + ((t + 1) & 1) * HN, hAlo + ((t + 1) & 1) * HN, cA,
                          hA + (t & 1) * HN, hAlo + (t & 1) * HN, nullptr, t, T);
  } else {
    int t = wv - 1;
    if (t < 0) return;
    lstm_tile_core<true>(tile, nullptr, bcB, whhB_hi, whhB_lo, wihB, hA + (t & 1) * HN,
                         hB + ((t + 1) & 1) * HN, hBlo + ((t + 1) & 1) * HN, cB,
                         hB + (t & 1) * HN, hBlo + (t & 1) * HN, hsB, t, T);
  }
}

// ---------------- MHA (fp32) ----------------
__global__ __launch_bounds__(256) void mha_kernel(const float* __restrict__ Qf,
                                                  const float* __restrict__ Kf,
                                                  const float* __restrict__ Vf,
                                                  ushort_t* __restrict__ attnout) {
  __shared__ float Qs[19][132];
  __shared__ float Ks[80][132];
  __shared__ float Ss[19][80];
  int h = blockIdx.x, b = blockIdx.y;
  int tid = threadIdx.x;
  for (int idx = tid; idx < 19 * 128; idx += 256) {
    int q = idx >> 7, d = idx & 127;
    Qs[q][d] = Qf[((size_t)(b * TD_ + q)) * H_ + h * 128 + d];
  }
  for (int idx = tid; idx < 80 * 128; idx += 256) {
    int k = idx >> 7, d = idx & 127;
    Ks[k][d] = Kf[((size_t)(b * TV_ + k)) * H_ + h * 128 + d];
  }
  __syncthreads();
  for (int u = tid; u < 240; u += 256) {
    int k = u / 3, qo = u % 3;
    int q0 = qo * 8;
    int nq = (qo == 2) ? 3 : 8;
    float s[8] = {0.f, 0.f, 0.f, 0.f, 0.f, 0.f, 0.f, 0.f};
    for (int d = 0; d < 128; d += 4) {
      float4 kv = *reinterpret_cast<const float4*>(&Ks[k][d]);
#pragma unroll
      for (int qi = 0; qi < 8; ++qi) {
        if (qi < nq) {
          float4 qv = *reinterpret_cast<const float4*>(&Qs[q0 + qi][d]);
          s[qi] += qv.x * kv.x + qv.y * kv.y + qv.z * kv.z + qv.w * kv.w;
        }
      }
    }
    for (int qi = 0; qi < nq; ++qi) Ss[q0 + qi][k] = s[qi] * 0.08838834764831845f;
  }
  __syncthreads();
  if (tid < 19) {
    float m = -1e30f;
    for (int k = 0; k < 80; ++k) m = fmaxf(m, Ss[tid][k]);
    float sum = 0.f;
    for (int k = 0; k < 80; ++k) {
      float e = expf(Ss[tid][k] - m);
      Ss[tid][k] = e;
      sum += e;
    }
    float inv = 1.0f / sum;
    for (int k = 0; k < 80; ++k) Ss[tid][k] *= inv;
  }
  __syncthreads();
  for (int u = tid; u < 160; u += 256) {
    int qp = u / 16, d0 = (u % 16) * 8;
    int q0 = qp * 2;
    int nq = (q0 + 1 < 19) ? 2 : 1;
    float o0[8] = {0.f, 0.f, 0.f, 0.f, 0.f, 0.f, 0.f, 0.f};
    float o1[8] = {0.f, 0.f, 0.f, 0.f, 0.f, 0.f, 0.f, 0.f};
#pragma unroll 4
    for (int k = 0; k < 80; ++k) {
      const float* vp = Vf + ((size_t)(b * TV_ + k)) * H_ + h * 128 + d0;
      float4 v0 = *reinterpret_cast<const float4*>(vp);
      float4 v1 = *reinterpret_cast<const float4*>(vp + 4);
      float p0 = Ss[q0][k];
      o0[0] += p0 * v0.x; o0[1] += p0 * v0.y; o0[2] += p0 * v0.z; o0[3] += p0 * v0.w;
      o0[4] += p0 * v1.x; o0[5] += p0 * v1.y; o0[6] += p0 * v1.z; o0[7] += p0 * v1.w;
      if (nq == 2) {
        float p1 = Ss[q0 + 1][k];
        o1[0] += p1 * v0.x; o1[1] += p1 * v0.y; o1[2] += p1 * v0.z; o1[3] += p1 * v0.w;
        o1[4] += p1 * v1.x; o1[5] += p1 * v1.y; o1[6] += p1 * v1.z; o1[7] += p1 * v1.w;
      }
    }
    for (int j = 0; j < 8; ++j)
      attnout[((size_t)(b * TD_ + q0)) * H_ + h * 128 + d0 + j] = f2bf(o0[j]);
    if (nq == 2)
      for (int j = 0; j < 8; ++j)
        attnout[((size_t)(b * TD_ + q0 + 1)) * H_ + h * 128 + d0 + j] = f2bf(o1[j]);
  }
}

// ---------------- host ----------------
extern "C" void kernel_launch(void* const* d_in, const int* in_sizes, int n_in, void* d_out,
                              int out_size, void* d_ws, size_t ws_size, hipStream_t stream) {
  const float* video = (const float*)d_in[0];
  const int* captions = (const int*)d_in[1];
  const float* vpw = (const float*)d_in[2];
  const float* vpb = (const float*)d_in[3];
  const float* emb_table = (const float*)d_in[4];
  const float* wih[4] = {(const float*)d_in[5], (const float*)d_in[9], (const float*)d_in[13],
                         (const float*)d_in[17]};
  const float* whh[4] = {(const float*)d_in[6], (const float*)d_in[10], (const float*)d_in[14],
                         (const float*)d_in[18]};
  const float* bih[4] = {(const float*)d_in[7], (const float*)d_in[11], (const float*)d_in[15],
                         (const float*)d_in[19]};
  const float* bhh[4] = {(const float*)d_in[8], (const float*)d_in[12], (const float*)d_in[16],
                         (const float*)d_in[20]};
  const float* a_inw = (const float*)d_in[21];
  const float* a_inb = (const float*)d_in[22];
  const float* a_outw = (const float*)d_in[23];
  const float* a_outb = (const float*)d_in[24];
  const float* ow = (const float*)d_in[25];
  const float* ob = (const float*)d_in[26];
  float* out = (float*)d_out;

  char* ws = (char*)d_ws;
  size_t o = 0;
  auto take = [&](size_t bytes) {
    size_t cur = o;
    o += (bytes + 255) & ~(size_t)255;
    return cur;
  };
  const size_t o_vpw = take((size_t)H_ * VD_ * 2);
  size_t o_wih_std[4], o_whhp_hi[4], o_whhp_lo[4], o_wihp[4], o_bc[4];
  for (int i = 0; i < 4; ++i) {
    o_wih_std[i] = (i == 0 || i == 2) ? take((size_t)G4_ * H_ * 2) : 0;
    o_whhp_hi[i] = take((size_t)G4_ * H_ * 2);
    o_whhp_lo[i] = take((size_t)G4_ * H_ * 2);
    o_wihp[i] = (i == 1 || i == 3) ? take((size_t)G4_ * H_ * 2) : 0;
    o_bc[i] = (i == 1 || i == 3) ? take((size_t)G4_ * 4) : 0;
  }
  const size_t o_ainw = take((size_t)3 * H_ * H_ * 2);
  const size_t o_aoutw = take((size_t)H_ * H_ * 2);
  const size_t o_ow = take((size_t)NV_ * H_ * 2);
  const size_t o_vproj = take((size_t)B_ * TV_ * H_ * 2);
  const size_t o_xg = take((size_t)B_ * TV_ * G4_ * 4);  // 41.94 MB; also video_bf & Q/K/V overlay
  const size_t o_hse1 = take((size_t)B_ * TV_ * H_ * 2);
  const size_t o_emb = take((size_t)B_ * TD_ * H_ * 2);
  const size_t o_attn = take((size_t)B_ * TD_ * H_ * 2);
  const size_t o_attd = take((size_t)B_ * TD_ * H_ * 2);
  const size_t o_hsd1 = take((size_t)B_ * TD_ * H_ * 2);
  const size_t o_state = take(786432);  // hA,hAlo,cA,hB,hBlo,cB

  ushort_t* vpw_bf = (ushort_t*)(ws + o_vpw);
  ushort_t* ainw_bf = (ushort_t*)(ws + o_ainw);
  ushort_t* aoutw_bf = (ushort_t*)(ws + o_aoutw);
  ushort_t* ow_bf = (ushort_t*)(ws + o_ow);
  ushort_t* vproj_bf = (ushort_t*)(ws + o_vproj);
  float* xg = (float*)(ws + o_xg);
  ushort_t* video_bf = (ushort_t*)(ws + o_xg);  // overlay (dead before xg0 written)
  ushort_t* hse1 = (ushort_t*)(ws + o_hse1);
  ushort_t* emb_bf = (ushort_t*)(ws + o_emb);
  ushort_t* attn_bf = (ushort_t*)(ws + o_attn);
  ushort_t* attd_bf = (ushort_t*)(ws + o_attd);
  ushort_t* hsd1 = (ushort_t*)(ws + o_hsd1);
  // Q/K/V fp32 overlay on xg region (dead during attention)
  float* Qf = (float*)(ws + o_xg);
  float* Kf = (float*)(ws + o_xg + 2490368);
  float* Vf = (float*)(ws + o_xg + 2490368 + 10485760);
  // state
  ushort_t* hA = (ushort_t*)(ws + o_state);
  ushort_t* hAlo = (ushort_t*)(ws + o_state + 131072);
  float* cA = (float*)(ws + o_state + 262144);
  ushort_t* hB = (ushort_t*)(ws + o_state + 393216);
  ushort_t* hBlo = (ushort_t*)(ws + o_state + 524288);
  float* cB = (float*)(ws + o_state + 655360);

  auto cvt = [&](const float* in, ushort_t* outp, size_t n) {
    int n4 = (int)(n / 4);
    cvt_f32_bf16<<<dim3((n4 + 255) / 256), dim3(256), 0, stream>>>(in, outp, n4);
  };
  cvt(vpw, vpw_bf, (size_t)H_ * VD_);
  cvt(video, video_bf, (size_t)B_ * TV_ * VD_);
  for (int i = 0; i < 4; ++i) {
    permute_split_whh<<<dim3(G4_), dim3(64), 0, stream>>>(
        whh[i], (ushort_t*)(ws + o_whhp_hi[i]), (ushort_t*)(ws + o_whhp_lo[i]));
    if (i == 0 || i == 2) {
      cvt(wih[i], (ushort_t*)(ws + o_wih_std[i]), (size_t)G4_ * H_);
    } else {
      permute_cvt_wih<<<dim3(G4_), dim3(64), 0, stream>>>(wih[i], (ushort_t*)(ws + o_wihp[i]));
      combine_bias_perm<<<dim3(G4_ / 256), dim3(256), 0, stream>>>(bih[i], bhh[i],
                                                                   (float*)(ws + o_bc[i]));
    }
  }
  cvt(a_inw, ainw_bf, (size_t)3 * H_ * H_);
  cvt(a_outw, aoutw_bf, (size_t)H_ * H_);
  cvt(ow, ow_bf, (size_t)NV_ * H_);

  // vproj: (5120,4096) x (512,4096)^T -> bf16
  gemm_nt_big<ushort_t><<<dim3(2, 80), dim3(256), 0, stream>>>(video_bf, vpw_bf, vpb, nullptr,
                                                               vproj_bf, B_ * TV_, H_, VD_);
  // xg0 = vproj @ wih0^T + biases
  gemm_nt_big<float><<<dim3(8, 80), dim3(256), 0, stream>>>(
      vproj_bf, (const ushort_t*)(ws + o_wih_std[0]), bih[0], bhh[0], xg, B_ * TV_, G4_, H_);

  auto run_pair = [&](int la, int lb, int T, ushort_t* hs_out) {
    hipMemsetAsync(ws + o_state, 0, 786432, stream);
    for (int wv = 0; wv <= T; ++wv) {
      lstm_pair_step<<<dim3(256), dim3(256), 0, stream>>>(
          xg, (const ushort_t*)(ws + o_whhp_hi[la]), (const ushort_t*)(ws + o_whhp_lo[la]), hA,
          hAlo, cA, (const ushort_t*)(ws + o_whhp_hi[lb]), (const ushort_t*)(ws + o_whhp_lo[lb]),
          (const ushort_t*)(ws + o_wihp[lb]), (const float*)(ws + o_bc[lb]), hB, hBlo, cB,
          hs_out, wv, T);
    }
  };

  run_pair(0, 1, TV_, hse1);

  gather_embed<<<dim3(TD_, B_), dim3(256), 0, stream>>>(emb_table, captions, emb_bf);

  // Q (small M), K/V (big)
  gemm_nt_mfma<float><<<dim3(8, TD_), dim3(256), 0, stream>>>(emb_bf, ainw_bf, a_inb, nullptr,
                                                              Qf, B_ * TD_, H_, H_);
  gemm_nt_big<float><<<dim3(2, 80), dim3(256), 0, stream>>>(
      hse1, ainw_bf + (size_t)H_ * H_, a_inb + H_, nullptr, Kf, B_ * TV_, H_, H_);
  gemm_nt_big<float><<<dim3(2, 80), dim3(256), 0, stream>>>(
      hse1, ainw_bf + (size_t)2 * H_ * H_, a_inb + 2 * H_, nullptr, Vf, B_ * TV_, H_, H_);

  mha_kernel<<<dim3(4, B_), dim3(256), 0, stream>>>(Qf, Kf, Vf, attn_bf);

  gemm_nt_mfma<ushort_t><<<dim3(8, TD_), dim3(256), 0, stream>>>(attn_bf, aoutw_bf, a_outb,
                                                                 nullptr, attd_bf, B_ * TD_, H_, H_);
  // xg2 = attd @ wih2^T + biases (clobbers Q/K/V overlay — dead)
  gemm_nt_big<float><<<dim3(8, TD_), dim3(256), 0, stream>>>(
      attd_bf, (const ushort_t*)(ws + o_wih_std[2]), bih[2], bhh[2], xg, B_ * TD_, G4_, H_);

  run_pair(2, 3, TD_, hsd1);

  // logits: (1216,512) x (10000,512)^T + ob
  gemm_nt_big<float><<<dim3((NV_ + 255) / 256, TD_), dim3(256), 0, stream>>>(
      hsd1, ow_bf, ob, nullptr, out, B_ * TD_, NV_, H_);
}